// Round 1
// baseline (316.802 us; speedup 1.0000x reference)
//
#include <hip/hip_runtime.h>
#include <stdint.h>

static constexpr int Bc = 16, Cc = 256, Hc = 56, Wc = 56, Gc = 4, CGc = 64;
static constexpr int HWc = Hc * Wc;
static constexpr float EPSc = 1e-5f;

// ---------------------------------------------------------------------------
// K1: binarize + pack weights. grid = 3*256 blocks (one wave each).
// wbits layout: [i][tap][o]  (o fastest -> coalesced per-lane loads in k_conv)
// forward value of _bin_weight is scale[o]*sign(w - mean(w)); scale = mean|w|.
// ---------------------------------------------------------------------------
__global__ __launch_bounds__(64) void k_prep_w(
    const float* __restrict__ w, uint64_t* __restrict__ wbits,
    float* __restrict__ scales) {
  const int io = blockIdx.x;          // i*256 + o
  const int i = io >> 8, o = io & 255;
  const int lane = threadIdx.x;       // ci (input channel within group)
  const float* wp = w + (size_t)io * 576 + lane * 9;
  float v[9];
  float ssum = 0.f, sabs = 0.f;
#pragma unroll
  for (int t = 0; t < 9; ++t) {
    v[t] = wp[t];
    ssum += v[t];
    sabs += fabsf(v[t]);
  }
#pragma unroll
  for (int off = 32; off > 0; off >>= 1) {
    ssum += __shfl_down(ssum, off);
    sabs += __shfl_down(sabs, off);
  }
  const float mean = __shfl(ssum, 0) * (1.f / 576.f);
  const float scale = __shfl(sabs, 0) * (1.f / 576.f);
#pragma unroll
  for (int t = 0; t < 9; ++t) {
    unsigned long long m = __ballot(v[t] > mean);  // bit ci: sign(w-mean) > 0
    if (lane == 0) wbits[(i * 9 + t) * Cc + o] = m;
  }
  if (lane == 0) scales[io] = scale;
}

// ---------------------------------------------------------------------------
// K2: binarize + pack activations. bit ci of word = (x + bias > 0).
// abits layout: [b][g][h][w], one uint64 per (position, group).
// grid = B*G*H blocks of 64 threads (thread = w).
// ---------------------------------------------------------------------------
__global__ __launch_bounds__(64) void k_pack_x(
    const float* __restrict__ x, const float* __restrict__ bias,
    uint64_t* __restrict__ abits) {
  const int bid = blockIdx.x;             // (b*4+g)*56 + h
  const int h = bid % Hc;
  const int bg = bid / Hc;
  const int g = bg & 3;
  const int w = threadIdx.x;
  if (w >= Wc) return;
  const float* xp = x + (((size_t)(bg >> 2) * Cc + g * CGc) * Hc + h) * Wc + w;
  const float* bp = bias + g * CGc;
  uint64_t word = 0;
#pragma unroll
  for (int ci = 0; ci < CGc; ++ci) {
    const float s = xp[(size_t)ci * HWc] + bp[ci];
    word |= (uint64_t)(s > 0.f) << ci;
  }
  abits[(size_t)bid * Wc + w] = word;
}

// ---------------------------------------------------------------------------
// K3: 3-branch dilated grouped binary conv + conv bias + RPReLU + branch sum.
// block = one (b,h) row; thread = output channel o; per-tap dot via popcount.
// Writes pre-LN sums to `out` (d_out); k_ln normalizes in place afterwards.
// Padding taps contribute exactly 0 -> skipped via (row,col) bounds checks
// (uniform branches: h is block-uniform, w is loop-uniform).
// ---------------------------------------------------------------------------
__global__ __launch_bounds__(256) void k_conv(
    const uint64_t* __restrict__ abits, const uint64_t* __restrict__ wbits,
    const float* __restrict__ scales, const float* __restrict__ cb,
    const float* __restrict__ mv1, const float* __restrict__ al,
    const float* __restrict__ mv2, float* __restrict__ out) {
  __shared__ uint64_t a_lds[Gc * 11 * Wc];  // rows h-5..h+5, all 4 groups
  const int bid = blockIdx.x;               // b*56 + h
  const int b = bid / Hc, h = bid % Hc;
  const int t = threadIdx.x;                // output channel o
  const int g = t >> 6;

  for (int idx = t; idx < Gc * 11 * Wc; idx += 256) {
    const int w = idx % Wc;
    const int rem = idx / Wc;
    const int r = rem % 11;
    const int gg = rem / 11;
    const int row = h + r - 5;
    uint64_t v = 0;
    if (row >= 0 && row < Hc)
      v = abits[(((size_t)b * Gc + gg) * Hc + row) * Wc + w];
    a_lds[idx] = v;
  }
  __syncthreads();

  uint64_t wgt[3][9];
  float sc[3], cbv[3], m1[3], av[3], m2[3];
#pragma unroll
  for (int i = 0; i < 3; ++i) {
#pragma unroll
    for (int tap = 0; tap < 9; ++tap) wgt[i][tap] = wbits[(i * 9 + tap) * Cc + t];
    sc[i] = scales[i * Cc + t];
    cbv[i] = cb[i * Cc + t];
    m1[i] = mv1[i * Cc + t];
    av[i] = al[i * Cc + t];
    m2[i] = mv2[i * Cc + t];
  }

  const uint64_t* arow = a_lds + g * 11 * Wc;
  float* op = out + (((size_t)b * Cc + t) * Hc + h) * Wc;
  const int DIL[3] = {1, 3, 5};
  for (int w = 0; w < Wc; ++w) {
    float outv = 0.f;
#pragma unroll
    for (int i = 0; i < 3; ++i) {
      const int d = DIL[i];
      int dot = 0;
#pragma unroll
      for (int kh = 0; kh < 3; ++kh) {
        const int row = h + d * (kh - 1);
        if (row < 0 || row >= Hc) continue;
        const int rb = (5 + d * (kh - 1)) * Wc;
#pragma unroll
        for (int kw = 0; kw < 3; ++kw) {
          const int col = w + d * (kw - 1);
          if (col < 0 || col >= Wc) continue;
          dot += 64 - 2 * __popcll(wgt[i][kh * 3 + kw] ^ arow[rb + col]);
        }
      }
      float y = sc[i] * (float)dot + cbv[i] - m1[i];
      y = (y >= 0.f) ? y : av[i] * y;
      outv += y + m2[i];
    }
    op[w] = outv;
  }
}

// ---------------------------------------------------------------------------
// K4: channel LayerNorm, in place on d_out. block = one (b,h) row.
// ---------------------------------------------------------------------------
__global__ __launch_bounds__(256) void k_ln(
    float* __restrict__ out, const float* __restrict__ gamma,
    const float* __restrict__ beta) {
  __shared__ float psum[4][Wc], psq[4][Wc], mstat[Wc], rstat[Wc];
  const int bid = blockIdx.x;
  const int b = bid / Hc, h = bid % Hc;
  float* base = out + ((size_t)b * Cc * Hc + h) * Wc;  // + c*HWc + w
  const int t = threadIdx.x;
  if (t < 4 * Wc) {
    const int w = t % Wc;
    const int cq = t / Wc;
    float s = 0.f, sq = 0.f;
    for (int c = cq; c < Cc; c += 4) {
      const float v = base[(size_t)c * HWc + w];
      s += v;
      sq = fmaf(v, v, sq);
    }
    psum[cq][w] = s;
    psq[cq][w] = sq;
  }
  __syncthreads();
  if (t < Wc) {
    const float s = psum[0][t] + psum[1][t] + psum[2][t] + psum[3][t];
    const float sq = psq[0][t] + psq[1][t] + psq[2][t] + psq[3][t];
    const float mean = s * (1.f / 256.f);
    const float var = sq * (1.f / 256.f) - mean * mean;
    mstat[t] = mean;
    rstat[t] = rsqrtf(var + EPSc);
  }
  __syncthreads();
  for (int idx = t; idx < Cc * Wc; idx += 256) {
    const int c = idx / Wc;
    const int w = idx % Wc;
    const float v = base[(size_t)c * HWc + w];
    base[(size_t)c * HWc + w] = (v - mstat[w]) * rstat[w] * gamma[c] + beta[c];
  }
}

// ---------------------------------------------------------------------------
extern "C" void kernel_launch(void* const* d_in, const int* in_sizes, int n_in,
                              void* d_out, int out_size, void* d_ws, size_t ws_size,
                              hipStream_t stream) {
  const float* x     = (const float*)d_in[0];  // (16,256,56,56)
  const float* bias  = (const float*)d_in[1];  // (1,256,1,1)
  const float* w     = (const float*)d_in[2];  // (3,256,64,3,3)
  const float* cb    = (const float*)d_in[3];  // (3,256)
  const float* mv1   = (const float*)d_in[4];  // (3,256)
  const float* al    = (const float*)d_in[5];  // (3,256)
  const float* mv2   = (const float*)d_in[6];  // (3,256)
  const float* gamma = (const float*)d_in[7];  // (256,)
  const float* beta  = (const float*)d_in[8];  // (256,)
  float* out = (float*)d_out;

  uint8_t* ws = (uint8_t*)d_ws;
  uint64_t* abits = (uint64_t*)ws;                              // 200704 * 8 B
  uint64_t* wbits = (uint64_t*)(ws + (size_t)200704 * 8);       //   6912 * 8 B
  float* scales   = (float*)(ws + (size_t)200704 * 8 + 6912 * 8);  // 768 * 4 B

  hipLaunchKernelGGL(k_prep_w, dim3(3 * Cc), dim3(64), 0, stream, w, wbits, scales);
  hipLaunchKernelGGL(k_pack_x, dim3(Bc * Gc * Hc), dim3(64), 0, stream, x, bias, abits);
  hipLaunchKernelGGL(k_conv, dim3(Bc * Hc), dim3(256), 0, stream,
                     abits, wbits, scales, cb, mv1, al, mv2, out);
  hipLaunchKernelGGL(k_ln, dim3(Bc * Hc), dim3(256), 0, stream, out, gamma, beta);
}

// Round 2
// 268.779 us; speedup vs baseline: 1.1787x; 1.1787x over previous
//
#include <hip/hip_runtime.h>
#include <stdint.h>

static constexpr int Bc = 16, Cc = 256, Hc = 56, Wc = 56, Gc = 4, CGc = 64;
static constexpr int HWc = Hc * Wc;
static constexpr float EPSc = 1e-5f;

// ---------------------------------------------------------------------------
// K1: binarize + pack weights. grid = 3*256 blocks (one wave each).
// wbits layout: [i][tap][o]  (o fastest -> coalesced per-lane loads in k_conv)
// forward value of _bin_weight is scale[o]*sign(w - mean(w)); scale = mean|w|.
// ---------------------------------------------------------------------------
__global__ __launch_bounds__(64) void k_prep_w(
    const float* __restrict__ w, uint64_t* __restrict__ wbits,
    float* __restrict__ scales) {
  const int io = blockIdx.x;          // i*256 + o
  const int i = io >> 8, o = io & 255;
  const int lane = threadIdx.x;       // ci (input channel within group)
  const float* wp = w + (size_t)io * 576 + lane * 9;
  float v[9];
  float ssum = 0.f, sabs = 0.f;
#pragma unroll
  for (int t = 0; t < 9; ++t) {
    v[t] = wp[t];
    ssum += v[t];
    sabs += fabsf(v[t]);
  }
#pragma unroll
  for (int off = 32; off > 0; off >>= 1) {
    ssum += __shfl_down(ssum, off);
    sabs += __shfl_down(sabs, off);
  }
  const float mean = __shfl(ssum, 0) * (1.f / 576.f);
  const float scale = __shfl(sabs, 0) * (1.f / 576.f);
#pragma unroll
  for (int t = 0; t < 9; ++t) {
    unsigned long long m = __ballot(v[t] > mean);  // bit ci: sign(w-mean) > 0
    if (lane == 0) wbits[(i * 9 + t) * Cc + o] = m;
  }
  if (lane == 0) scales[io] = scale;
}

// ---------------------------------------------------------------------------
// K2: binarize + pack activations. bit ci of word = (x + bias > 0).
// abits layout: [b][g][h][w]. grid = B*G*H blocks of 64 threads (thread = w).
// Lane reads are consecutive-w -> coalesced 224B per instruction.
// ---------------------------------------------------------------------------
__global__ __launch_bounds__(64) void k_pack_x(
    const float* __restrict__ x, const float* __restrict__ bias,
    uint64_t* __restrict__ abits) {
  const int bid = blockIdx.x;             // (b*4+g)*56 + h
  const int h = bid % Hc;
  const int bg = bid / Hc;
  const int g = bg & 3;
  const int w = threadIdx.x;
  if (w >= Wc) return;
  const float* xp = x + (((size_t)(bg >> 2) * Cc + g * CGc) * Hc + h) * Wc + w;
  const float* bp = bias + g * CGc;
  uint64_t word = 0;
#pragma unroll
  for (int ci = 0; ci < CGc; ++ci) {
    const float s = xp[(size_t)ci * HWc] + bp[ci];
    word |= (uint64_t)(s > 0.f) << ci;
  }
  abits[(size_t)bid * Wc + w] = word;
}

// ---------------------------------------------------------------------------
// K3: fused 3-branch binary conv + bias + RPReLU + branch-sum + LayerNorm.
// block = one (b,h) row; thread = output channel o.
// Conv results go to LDS out_tile[256][57] (stride 57 -> bank-conflict-free),
// then cross-channel LN stats are computed in LDS and the normalized result
// is written with consecutive-lane = consecutive-w coalesced stores.
// LDS: 19712 (halo) + 58368 (tile) + 2240 (stats) = 80320 B -> 2 blocks/CU.
// ---------------------------------------------------------------------------
static constexpr int TS = 57;  // out_tile row stride (floats)

__global__ __launch_bounds__(256) void k_conv_ln(
    const uint64_t* __restrict__ abits, const uint64_t* __restrict__ wbits,
    const float* __restrict__ scales, const float* __restrict__ cb,
    const float* __restrict__ mv1, const float* __restrict__ al,
    const float* __restrict__ mv2, const float* __restrict__ gamma,
    const float* __restrict__ beta, float* __restrict__ out) {
  __shared__ uint64_t a_lds[Gc * 11 * Wc];   // 19712 B: rows h-5..h+5, 4 groups
  __shared__ float out_tile[Cc * TS];        // 58368 B
  __shared__ float redu[4][Wc], redq[4][Wc]; // 1792 B
  __shared__ float mstat[Wc], rstat[Wc];     // 448 B

  const int bid = blockIdx.x;               // b*56 + h
  const int b = bid / Hc, h = bid % Hc;
  const int t = threadIdx.x;                // output channel o
  const int g = t >> 6;

  // ---- stage activation halo rows ----
  for (int idx = t; idx < Gc * 11 * Wc; idx += 256) {
    const int w = idx % Wc;
    const int rem = idx / Wc;
    const int r = rem % 11;
    const int gg = rem / 11;
    const int row = h + r - 5;
    uint64_t v = 0;
    if (row >= 0 && row < Hc)
      v = abits[(((size_t)b * Gc + gg) * Hc + row) * Wc + w];
    a_lds[idx] = v;
  }
  __syncthreads();

  // ---- per-channel weights & epilogue params (registers) ----
  uint64_t wgt[3][9];
  float sc[3], cbv[3], m1[3], av[3], m2[3];
#pragma unroll
  for (int i = 0; i < 3; ++i) {
#pragma unroll
    for (int tap = 0; tap < 9; ++tap) wgt[i][tap] = wbits[(i * 9 + tap) * Cc + t];
    sc[i] = scales[i * Cc + t];
    cbv[i] = cb[i * Cc + t];
    m1[i] = mv1[i * Cc + t];
    av[i] = al[i * Cc + t];
    m2[i] = mv2[i * Cc + t];
  }

  // ---- conv main loop: results -> LDS tile ----
  const uint64_t* arow = a_lds + g * 11 * Wc;
  const int DIL[3] = {1, 3, 5};
  for (int w = 0; w < Wc; ++w) {
    float outv = 0.f;
#pragma unroll
    for (int i = 0; i < 3; ++i) {
      const int d = DIL[i];
      int dot0 = 0, dot1 = 0, dot2 = 0;  // per-kh accumulators (break dep chain)
#pragma unroll
      for (int kh = 0; kh < 3; ++kh) {
        const int row = h + d * (kh - 1);
        if (row < 0 || row >= Hc) continue;
        const int rb = (5 + d * (kh - 1)) * Wc;
        int acc = 0;
#pragma unroll
        for (int kw = 0; kw < 3; ++kw) {
          const int col = w + d * (kw - 1);
          if (col < 0 || col >= Wc) continue;
          acc += 64 - 2 * __popcll(wgt[i][kh * 3 + kw] ^ arow[rb + col]);
        }
        if (kh == 0) dot0 = acc; else if (kh == 1) dot1 = acc; else dot2 = acc;
      }
      const int dot = dot0 + dot1 + dot2;
      float y = sc[i] * (float)dot + cbv[i] - m1[i];
      y = (y >= 0.f) ? y : av[i] * y;
      outv += y + m2[i];
    }
    out_tile[t * TS + w] = outv;
  }
  __syncthreads();

  // ---- LN stats: 4 partial sums per w, then combine ----
  if (t < 4 * Wc) {
    const int w = t % Wc;
    const int cq = t / Wc;
    float s = 0.f, sq = 0.f;
#pragma unroll 4
    for (int c = cq * 64; c < cq * 64 + 64; ++c) {
      const float v = out_tile[c * TS + w];
      s += v;
      sq = fmaf(v, v, sq);
    }
    redu[cq][w] = s;
    redq[cq][w] = sq;
  }
  __syncthreads();
  if (t < Wc) {
    const float s = redu[0][t] + redu[1][t] + redu[2][t] + redu[3][t];
    const float sq = redq[0][t] + redq[1][t] + redq[2][t] + redq[3][t];
    const float mean = s * (1.f / 256.f);
    const float var = sq * (1.f / 256.f) - mean * mean;
    mstat[t] = mean;
    rstat[t] = rsqrtf(var + EPSc);
  }
  __syncthreads();

  // ---- normalize + coalesced store (consecutive lanes -> consecutive w) ----
  float* base = out + ((size_t)b * Cc * Hc + h) * Wc;  // + c*HWc + w
  for (int idx = t; idx < Cc * Wc; idx += 256) {
    const int c = idx / Wc;
    const int w = idx - c * Wc;
    const float v = out_tile[c * TS + w];
    base[(size_t)c * HWc + w] =
        (v - mstat[w]) * rstat[w] * gamma[c] + beta[c];
  }
}

// ---------------------------------------------------------------------------
extern "C" void kernel_launch(void* const* d_in, const int* in_sizes, int n_in,
                              void* d_out, int out_size, void* d_ws, size_t ws_size,
                              hipStream_t stream) {
  const float* x     = (const float*)d_in[0];  // (16,256,56,56)
  const float* bias  = (const float*)d_in[1];  // (1,256,1,1)
  const float* w     = (const float*)d_in[2];  // (3,256,64,3,3)
  const float* cb    = (const float*)d_in[3];  // (3,256)
  const float* mv1   = (const float*)d_in[4];  // (3,256)
  const float* al    = (const float*)d_in[5];  // (3,256)
  const float* mv2   = (const float*)d_in[6];  // (3,256)
  const float* gamma = (const float*)d_in[7];  // (256,)
  const float* beta  = (const float*)d_in[8];  // (256,)
  float* out = (float*)d_out;

  uint8_t* ws = (uint8_t*)d_ws;
  uint64_t* abits = (uint64_t*)ws;                              // 200704 * 8 B
  uint64_t* wbits = (uint64_t*)(ws + (size_t)200704 * 8);       //   6912 * 8 B
  float* scales   = (float*)(ws + (size_t)200704 * 8 + 6912 * 8);  // 768 * 4 B

  hipLaunchKernelGGL(k_prep_w, dim3(3 * Cc), dim3(64), 0, stream, w, wbits, scales);
  hipLaunchKernelGGL(k_pack_x, dim3(Bc * Gc * Hc), dim3(64), 0, stream, x, bias, abits);
  hipLaunchKernelGGL(k_conv_ln, dim3(Bc * Hc), dim3(256), 0, stream,
                     abits, wbits, scales, cb, mv1, al, mv2, gamma, beta, out);
}

// Round 3
// 192.193 us; speedup vs baseline: 1.6484x; 1.3985x over previous
//
#include <hip/hip_runtime.h>
#include <stdint.h>

static constexpr int Bc = 16, Cc = 256, Hc = 56, Wc = 56, Gc = 4, CGc = 64;
static constexpr int HWc = Hc * Wc;
static constexpr float EPSc = 1e-5f;

// ---------------------------------------------------------------------------
// K1 (fused): blocks [0,768): binarize+pack weights. blocks [768, 768+3584):
// binarize+pack activations. One launch instead of two.
// wbits layout: [i][tap][o] (o fastest); abits layout: [b][g][h][w].
// ---------------------------------------------------------------------------
__global__ __launch_bounds__(64) void k_prep(
    const float* __restrict__ w, const float* __restrict__ x,
    const float* __restrict__ bias, uint64_t* __restrict__ wbits,
    float* __restrict__ scales, uint64_t* __restrict__ abits) {
  if (blockIdx.x < 3 * Cc) {
    // ---- weight part ----
    const int io = blockIdx.x;          // i*256 + o
    const int i = io >> 8, o = io & 255;
    const int lane = threadIdx.x;       // ci
    const float* wp = w + (size_t)io * 576 + lane * 9;
    float v[9];
    float ssum = 0.f, sabs = 0.f;
#pragma unroll
    for (int t = 0; t < 9; ++t) {
      v[t] = wp[t];
      ssum += v[t];
      sabs += fabsf(v[t]);
    }
#pragma unroll
    for (int off = 32; off > 0; off >>= 1) {
      ssum += __shfl_down(ssum, off);
      sabs += __shfl_down(sabs, off);
    }
    const float mean = __shfl(ssum, 0) * (1.f / 576.f);
    const float scale = __shfl(sabs, 0) * (1.f / 576.f);
#pragma unroll
    for (int t = 0; t < 9; ++t) {
      unsigned long long m = __ballot(v[t] > mean);
      if (lane == 0) wbits[(i * 9 + t) * Cc + o] = m;
    }
    if (lane == 0) scales[io] = scale;
  } else {
    // ---- activation part ----
    const int bid = blockIdx.x - 3 * Cc;    // (b*4+g)*56 + h
    const int h = bid % Hc;
    const int bg = bid / Hc;
    const int g = bg & 3;
    const int ww = threadIdx.x;
    if (ww >= Wc) return;
    const float* xp = x + (((size_t)(bg >> 2) * Cc + g * CGc) * Hc + h) * Wc + ww;
    const float* bp = bias + g * CGc;
    uint64_t word = 0;
#pragma unroll
    for (int ci = 0; ci < CGc; ++ci) {
      const float s = xp[(size_t)ci * HWc] + bp[ci];
      word |= (uint64_t)(s > 0.f) << ci;
    }
    abits[(size_t)bid * Wc + ww] = word;
  }
}

// ---------------------------------------------------------------------------
// Per-branch state for the fully-unrolled conv. D = dilation (compile-time).
// Row-validity (runtime, block-uniform) handled WITHOUT branches: invalid
// rows read a zeroed LDS row; a tap reading 0 contributes 64-2*popc(wgt)=z,
// pre-subtracted via the B{L,M,R} constants. Col-validity is compile-time
// (w is unrolled) so invalid-col taps are simply not emitted.
//   dot_true(w) = B(w) - 2 * sum_over_emitted_taps popc(wgt ^ a)
// ---------------------------------------------------------------------------
template <int D>
struct Branch {
  uint64_t wgt[9];
  const uint64_t *r0, *r1, *r2;   // row pointers (kh = 0,1,2)
  int BL, BM, BR;
  float sc, cbm1, al;

  __device__ __forceinline__ void init(const uint64_t* __restrict__ wb,
                                       const uint64_t* arow,
                                       const uint64_t* zrow, int h,
                                       float sc_, float cbm1_, float al_) {
    sc = sc_; cbm1 = cbm1_; al = al_;
    int z[9];
#pragma unroll
    for (int k = 0; k < 9; ++k) {
      wgt[k] = wb[k * Cc];
      z[k] = 64 - 2 * (int)__popcll(wgt[k]);
    }
    const bool v0 = (h - D >= 0), v2 = (h + D < Hc);
    r0 = v0 ? (arow + (5 - D) * Wc) : zrow;
    r1 = arow + 5 * Wc;
    r2 = v2 ? (arow + (5 + D) * Wc) : zrow;
    const int Z0 = (v0 ? 0 : z[0]) + (v2 ? 0 : z[6]);
    const int Z1 = (v0 ? 0 : z[1]) + (v2 ? 0 : z[7]);
    const int Z2 = (v0 ? 0 : z[2]) + (v2 ? 0 : z[8]);
    BM = 576 - Z0 - Z1 - Z2;   // 9 taps emitted
    BL = 384 - Z1 - Z2;        // w <  D: kw=0 column dropped (6 taps)
    BR = 384 - Z0 - Z1;        // w >= 56-D: kw=2 column dropped
  }

  // w must be a compile-time constant at each (inlined, unrolled) call site.
  __device__ __forceinline__ float eval(int w) const {
    int P = 0;
#pragma unroll
    for (int kh = 0; kh < 3; ++kh) {
      const uint64_t* rp = (kh == 0) ? r0 : (kh == 1 ? r1 : r2);
#pragma unroll
      for (int kw = 0; kw < 3; ++kw) {
        const int col = w + D * (kw - 1);
        if (col < 0 || col >= Wc) continue;   // folds at compile time
        P += (int)__popcll(wgt[kh * 3 + kw] ^ rp[col]);
      }
    }
    const int B = (w < D) ? BL : ((w >= Wc - D) ? BR : BM);
    const float y0 = fmaf(sc, (float)(B - 2 * P), cbm1);
    return (y0 >= 0.f) ? y0 : al * y0;
  }
};

// ---------------------------------------------------------------------------
// K2: fused conv(3 branches) + bias + RPReLU + sum + LayerNorm.
// block = one (b,h) row; thread = output channel o. LDS:
//   a_lds: 4 groups x 11 halo rows x 56 + 56-word zero row  = 20160 B
//   out_tile[256][57]                                        = 58368 B
//   stats                                                    =  2240 B
// total 80768 B -> 2 blocks/CU.
// ---------------------------------------------------------------------------
static constexpr int TS = 57;
static constexpr int ZOFF = Gc * 11 * Wc;  // zero-row offset in a_lds (u64s)

__global__ __launch_bounds__(256) void k_conv_ln(
    const uint64_t* __restrict__ abits, const uint64_t* __restrict__ wbits,
    const float* __restrict__ scales, const float* __restrict__ cb,
    const float* __restrict__ mv1, const float* __restrict__ al,
    const float* __restrict__ mv2, const float* __restrict__ gamma,
    const float* __restrict__ beta, float* __restrict__ out) {
  __shared__ uint64_t a_lds[Gc * 11 * Wc + Wc];
  __shared__ float out_tile[Cc * TS];
  __shared__ float redu[4][Wc], redq[4][Wc];
  __shared__ float mstat[Wc], rstat[Wc];

  const int bid = blockIdx.x;               // b*56 + h
  const int b = bid / Hc, h = bid % Hc;
  const int t = threadIdx.x;                // output channel o
  const int g = t >> 6;

  // ---- stage halo + zero row ----
  for (int idx = t; idx < Gc * 11 * Wc; idx += 256) {
    const int w = idx % Wc;
    const int rem = idx / Wc;
    const int r = rem % 11;
    const int gg = rem / 11;
    const int row = h + r - 5;
    uint64_t v = 0;
    if (row >= 0 && row < Hc)
      v = abits[(((size_t)b * Gc + gg) * Hc + row) * Wc + w];
    a_lds[idx] = v;
  }
  if (t < Wc) a_lds[ZOFF + t] = 0;
  __syncthreads();

  // ---- per-branch setup (weights, scalars, row ptrs, corrections) ----
  const uint64_t* arow = a_lds + g * 11 * Wc;
  const uint64_t* zrow = a_lds + ZOFF;
  Branch<1> b0; Branch<3> b1; Branch<5> b2;
  b0.init(wbits + 0 * 9 * Cc + t, arow, zrow, h, scales[0 * Cc + t],
          cb[0 * Cc + t] - mv1[0 * Cc + t], al[0 * Cc + t]);
  b1.init(wbits + 1 * 9 * Cc + t, arow, zrow, h, scales[1 * Cc + t],
          cb[1 * Cc + t] - mv1[1 * Cc + t], al[1 * Cc + t]);
  b2.init(wbits + 2 * 9 * Cc + t, arow, zrow, h, scales[2 * Cc + t],
          cb[2 * Cc + t] - mv1[2 * Cc + t], al[2 * Cc + t]);
  const float m2sum = mv2[0 * Cc + t] + mv2[1 * Cc + t] + mv2[2 * Cc + t];

  // ---- fully-unrolled conv row: immediate LDS offsets, branch-free ----
#pragma unroll
  for (int w = 0; w < Wc; ++w) {
    const float outv = m2sum + b0.eval(w) + b1.eval(w) + b2.eval(w);
    out_tile[t * TS + w] = outv;
  }
  __syncthreads();

  // ---- LN stats ----
  if (t < 4 * Wc) {
    const int w = t % Wc;
    const int cq = t / Wc;
    float s = 0.f, sq = 0.f;
#pragma unroll 4
    for (int c = cq * 64; c < cq * 64 + 64; ++c) {
      const float v = out_tile[c * TS + w];
      s += v;
      sq = fmaf(v, v, sq);
    }
    redu[cq][w] = s;
    redq[cq][w] = sq;
  }
  __syncthreads();
  if (t < Wc) {
    const float s = redu[0][t] + redu[1][t] + redu[2][t] + redu[3][t];
    const float sq = redq[0][t] + redq[1][t] + redq[2][t] + redq[3][t];
    const float mean = s * (1.f / 256.f);
    const float var = sq * (1.f / 256.f) - mean * mean;
    mstat[t] = mean;
    rstat[t] = rsqrtf(var + EPSc);
  }
  __syncthreads();

  // ---- normalize + coalesced store ----
  float* base = out + ((size_t)b * Cc * Hc + h) * Wc;
  for (int idx = t; idx < Cc * Wc; idx += 256) {
    const int c = idx / Wc;
    const int w = idx - c * Wc;
    const float v = out_tile[c * TS + w];
    base[(size_t)c * HWc + w] = (v - mstat[w]) * rstat[w] * gamma[c] + beta[c];
  }
}

// ---------------------------------------------------------------------------
extern "C" void kernel_launch(void* const* d_in, const int* in_sizes, int n_in,
                              void* d_out, int out_size, void* d_ws, size_t ws_size,
                              hipStream_t stream) {
  const float* x     = (const float*)d_in[0];
  const float* bias  = (const float*)d_in[1];
  const float* w     = (const float*)d_in[2];
  const float* cb    = (const float*)d_in[3];
  const float* mv1   = (const float*)d_in[4];
  const float* al    = (const float*)d_in[5];
  const float* mv2   = (const float*)d_in[6];
  const float* gamma = (const float*)d_in[7];
  const float* beta  = (const float*)d_in[8];
  float* out = (float*)d_out;

  uint8_t* ws = (uint8_t*)d_ws;
  uint64_t* abits = (uint64_t*)ws;                                 // 200704*8 B
  uint64_t* wbits = (uint64_t*)(ws + (size_t)200704 * 8);          //   6912*8 B
  float* scales   = (float*)(ws + (size_t)200704 * 8 + 6912 * 8);  //    768*4 B

  hipLaunchKernelGGL(k_prep, dim3(3 * Cc + Bc * Gc * Hc), dim3(64), 0, stream,
                     w, x, bias, wbits, scales, abits);
  hipLaunchKernelGGL(k_conv_ln, dim3(Bc * Hc), dim3(256), 0, stream,
                     abits, wbits, scales, cb, mv1, al, mv2, gamma, beta, out);
}